// Round 2
// baseline (209.714 us; speedup 1.0000x reference)
//
#include <hip/hip_runtime.h>
#include <stdint.h>

#define N_NODES 50000
#define N_EDGES 800000
#define IN_C 64
#define HID 128
#define OUT_C 2
#define N_GRAPHS 64
#define NBUCK 196                    // ceil(N_NODES/256) buckets of 256 nodes
#define BCAP 6144                    // bucket capacity (mean 4096, sd ~64)
#define ECH 4096                     // edges per phase-A block

typedef long long i64;
typedef __attribute__((ext_vector_type(8))) short bf8;    // 8 bf16 = 4 VGPRs
typedef __attribute__((ext_vector_type(4))) float f32x4;  // MFMA C/D frag

__device__ __forceinline__ float bf2f(ushort h) {
    return __uint_as_float(((uint)h) << 16);
}
__device__ __forceinline__ ushort f2bf(float f) {
    uint x = __float_as_uint(f);
    uint r = x + 0x7fffu + ((x >> 16) & 1u);   // RNE
    return (ushort)(r >> 16);
}
__device__ __forceinline__ float loadf(const void* p, size_t i, int bf) {
    return bf ? bf2f(((const ushort*)p)[i]) : ((const float*)p)[i];
}
__device__ __forceinline__ int clampi(int v, int lo, int hi) {
    return min(max(v, lo), hi);
}

__device__ __forceinline__ int edge_src(const void* ei, int e, int wide) {
    return wide ? (int)((const i64*)ei)[e] : ((const int*)ei)[e];
}
__device__ __forceinline__ int edge_dst(const void* ei, int e, int wide) {
    return wide ? (int)((const i64*)ei)[N_EDGES + e] : ((const int*)ei)[N_EDGES + e];
}
__device__ __forceinline__ i64 batch_at(const void* b, int i, int wide) {
    return wide ? ((const i64*)b)[i] : (i64)((const int*)b)[i];
}

// unpack a uint4 (8 bf16) into 8 floats / accumulate
__device__ __forceinline__ void bset(float* a, uint4 u) {
    a[0] = bf2f((ushort)(u.x & 0xffffu)); a[1] = bf2f((ushort)(u.x >> 16));
    a[2] = bf2f((ushort)(u.y & 0xffffu)); a[3] = bf2f((ushort)(u.y >> 16));
    a[4] = bf2f((ushort)(u.z & 0xffffu)); a[5] = bf2f((ushort)(u.z >> 16));
    a[6] = bf2f((ushort)(u.w & 0xffffu)); a[7] = bf2f((ushort)(u.w >> 16));
}
__device__ __forceinline__ void bacc(float* a, uint4 u) {
    a[0] += bf2f((ushort)(u.x & 0xffffu)); a[1] += bf2f((ushort)(u.x >> 16));
    a[2] += bf2f((ushort)(u.y & 0xffffu)); a[3] += bf2f((ushort)(u.y >> 16));
    a[4] += bf2f((ushort)(u.z & 0xffffu)); a[5] += bf2f((ushort)(u.z >> 16));
    a[6] += bf2f((ushort)(u.w & 0xffffu)); a[7] += bf2f((ushort)(u.w >> 16));
}
__device__ __forceinline__ uint pk2(float lo, float hi) {
    return ((uint)f2bf(hi) << 16) | (uint)f2bf(lo);
}
// 8 f32 * dv -> MFMA bf16 A-fragment (8 bf16)
__device__ __forceinline__ bf8 packbf8(const float* a, float dv) {
    union { bf8 v; uint u[4]; } r;
    r.u[0] = pk2(a[0] * dv, a[1] * dv);
    r.u[1] = pk2(a[2] * dv, a[3] * dv);
    r.u[2] = pk2(a[4] * dv, a[5] * dv);
    r.u[3] = pk2(a[6] * dv, a[7] * dv);
    return r.v;
}

// ---- init: zero bcnt/gbuf; block 0 also runs the dtype probes ----
__global__ __launch_bounds__(256) void k_init(const uint* __restrict__ braw,
                                              const uint* __restrict__ xraw,
                                              int* __restrict__ bcnt,
                                              float* __restrict__ gbuf,
                                              int* __restrict__ iflag,
                                              int* __restrict__ fflag) {
    int i = blockIdx.x * blockDim.x + threadIdx.x;
    if (i < N_GRAPHS * HID) gbuf[i] = 0.f;
    if (i < NBUCK) bcnt[i] = 0;
    if (blockIdx.x == 0) {
        __shared__ uint si[128];
        __shared__ int sf[256];
        int t = threadIdx.x;
        if (t < 128) si[t] = (t < 100) ? braw[25001 + 2 * t] : 0u;
        uint e = (xraw[t] >> 7) & 0xFFu;
        sf[t] = (e >= 100u && e <= 140u) ? 1 : 0;
        __syncthreads();
        for (int off = 128; off > 0; off >>= 1) {
            if (t < off) {
                sf[t] += sf[t + off];
                if (off <= 64 && t < 64) si[t] |= si[t + off];
            }
            __syncthreads();
        }
        if (t == 0) {
            *iflag = (si[0] == 0u) ? 1 : 0;   // 1 = int64, 0 = int32
            *fflag = (sf[0] >= 192) ? 1 : 0;  // 1 = bf16,  0 = f32
        }
    }
}

// ---- phase A: bin edges by dst>>8 via LDS-sorted staging; contiguous runs.
// 1024 threads/block. Threads t<256 of blocks 0..95 also transpose W1/W2. ----
__global__ __launch_bounds__(1024) void k_binA(const void* __restrict__ ei,
                                               const int* __restrict__ iflag,
                                               const int* __restrict__ fflag,
                                               const void* __restrict__ W1,
                                               const void* __restrict__ W2,
                                               ushort* __restrict__ Wt1,
                                               ushort* __restrict__ Wt2,
                                               int* __restrict__ bcnt,
                                               uint2* __restrict__ bmem) {
    int t = threadIdx.x;
    if (t < 256 && blockIdx.x < (IN_C * HID + HID * HID) / 256) {
        int ff = *fflag;
        int idx = blockIdx.x * 256 + t;
        if (idx < IN_C * HID) {
            int k = idx >> 7, n = idx & 127;
            Wt1[n * IN_C + k] = f2bf(loadf(W1, idx, ff));
        } else {
            int j = idx - IN_C * HID;
            int k = j >> 7, n = j & 127;
            Wt2[n * HID + k] = f2bf(loadf(W2, j, ff));
        }
    }
    int wide = *iflag;
    __shared__ int cnt[NBUCK];
    __shared__ int obase[NBUCK];
    __shared__ int run[NBUCK];
    __shared__ int gbase[NBUCK];
    __shared__ int sc[256];
    __shared__ uint2 stage[ECH];
    int e0 = blockIdx.x * ECH;
    int m = min(ECH, N_EDGES - e0);
    for (int i = t; i < NBUCK; i += 1024) cnt[i] = 0;
    __syncthreads();
    for (int i = t; i < m; i += 1024) {
        int d = edge_dst(ei, e0 + i, wide);
        atomicAdd(&cnt[d >> 8], 1);
    }
    __syncthreads();
    int cv = (t < NBUCK) ? cnt[t] : 0;
    if (t < 256) sc[t] = cv;
    __syncthreads();
    for (int off = 1; off < 256; off <<= 1) {
        int v = (t >= off && t < 256) ? sc[t - off] : 0;
        __syncthreads();
        if (t < 256) sc[t] += v;
        __syncthreads();
    }
    if (t < NBUCK) {
        int ex = sc[t] - cv;
        obase[t] = ex;
        run[t] = ex;
        gbase[t] = (cv > 0) ? atomicAdd(&bcnt[t], cv) : 0;
    }
    __syncthreads();
    for (int i = t; i < m; i += 1024) {
        int s = edge_src(ei, e0 + i, wide);
        int d = edge_dst(ei, e0 + i, wide);
        int slot = atomicAdd(&run[d >> 8], 1);
        uint2 pr; pr.x = (uint)s; pr.y = (uint)d;
        stage[slot] = pr;
    }
    __syncthreads();
    for (int i = t; i < m; i += 1024) {
        uint2 pr = stage[i];
        int b = (int)(pr.y >> 8);
        int pos = gbase[b] + (i - obase[b]);
        if (pos < BCAP) bmem[(size_t)b * BCAP + pos] = pr;
    }
}

// ---- phase B: per-bucket LDS counting-sort -> offs/csr/dinv (coalesced),
// self-scans bcnt, writes Y1 = bf16(dinv * x) with vector IO. 1024 thr. ----
__global__ __launch_bounds__(1024) void k_binB(const uint2* __restrict__ bmem,
                                               const int* __restrict__ bcnt,
                                               const void* __restrict__ x,
                                               const int* __restrict__ fflag,
                                               int* __restrict__ offs,
                                               int* __restrict__ csr,
                                               float* __restrict__ dinv,
                                               ushort* __restrict__ Y1) {
    int b = blockIdx.x;
    int t = threadIdx.x;
    int node0 = b << 8;
    __shared__ int sc[256];
    __shared__ int degl[256];
    __shared__ int run[256];
    __shared__ float sdinv[256];
    __shared__ int sbase, scnt;
    __shared__ int stage[BCAP];
    int v = (t < NBUCK) ? bcnt[t] : 0;
    if (t < 256) sc[t] = v;
    __syncthreads();
    for (int off = 1; off < 256; off <<= 1) {
        int u = (t >= off && t < 256) ? sc[t - off] : 0;
        __syncthreads();
        if (t < 256) sc[t] += u;
        __syncthreads();
    }
    if (t == b) {
        int c = clampi(v, 0, BCAP);
        scnt = c;
        sbase = clampi(sc[t] - v, 0, N_EDGES - c);
    }
    if (t < 256) degl[t] = 0;
    __syncthreads();
    int cnt = scnt;
    int base = sbase;
    for (int i = t; i < cnt; i += 1024) {
        uint2 pr = bmem[(size_t)b * BCAP + i];
        atomicAdd(&degl[pr.y & 255], 1);
    }
    __syncthreads();
    int dv = (t < 256) ? degl[t] : 0;
    if (t < 256) sc[t] = dv;
    __syncthreads();
    for (int off = 1; off < 256; off <<= 1) {
        int u = (t >= off && t < 256) ? sc[t - off] : 0;
        __syncthreads();
        if (t < 256) sc[t] += u;
        __syncthreads();
    }
    if (t < 256) {
        int ex = sc[t] - dv;
        run[t] = ex;
        float di = rsqrtf((float)(dv + 1));
        sdinv[t] = di;
        int n = node0 + t;
        if (n < N_NODES) { offs[n] = base + ex; dinv[n] = di; }
    }
    if (b == 0 && t == 0) offs[N_NODES] = N_EDGES;
    __syncthreads();
    for (int i = t; i < cnt; i += 1024) {
        uint2 pr = bmem[(size_t)b * BCAP + i];
        int slot = atomicAdd(&run[pr.y & 255], 1);
        stage[clampi(slot, 0, BCAP - 1)] = (int)pr.x;
    }
    __syncthreads();
    for (int i = t; i < cnt; i += 1024) csr[base + i] = stage[i];
    int ff = *fflag;
    for (int idx = t; idx < 256 * (IN_C / 4); idx += 1024) {
        int nl = idx >> 4, c4 = (idx & 15) * 4;
        int nn = node0 + nl;
        if (nn < N_NODES) {
            float x0, x1, x2, x3;
            if (ff) {
                ushort4 u = *(const ushort4*)((const ushort*)x + (size_t)nn * IN_C + c4);
                x0 = bf2f(u.x); x1 = bf2f(u.y); x2 = bf2f(u.z); x3 = bf2f(u.w);
            } else {
                float4 vv = *(const float4*)((const float*)x + (size_t)nn * IN_C + c4);
                x0 = vv.x; x1 = vv.y; x2 = vv.z; x3 = vv.w;
            }
            float di = sdinv[nl];
            ushort4 o;
            o.x = f2bf(x0 * di); o.y = f2bf(x1 * di);
            o.z = f2bf(x2 * di); o.w = f2bf(x3 * di);
            *(ushort4*)(Y1 + (size_t)nn * IN_C + c4) = o;
        }
    }
}

// ---- R18: fused layer 1 = gather-into-A-fragment + MFMA.
// Wave = 16 nodes. Lane (m16,q) gather-accumulates Y1 channel slices
// [q*8,+8) and [32+q*8,+8) for node rowbase+m16 directly in registers
// (exactly the MFMA A-frag layout), then h1s = relu(agg@W1+b1)*dinv.
// Kills the Mbuf round-trip (12.8 MB) + one launch. ----
__global__ __launch_bounds__(256) void k_l1(const ushort* __restrict__ Y1,
                                            const float* __restrict__ dinv,
                                            const int* __restrict__ offs,
                                            const int* __restrict__ csr,
                                            const ushort* __restrict__ Wt,
                                            const int* __restrict__ fflag,
                                            const void* __restrict__ bias,
                                            ushort* __restrict__ out) {
    int ff = *fflag;
    int wave = threadIdx.x >> 6;
    int lane = threadIdx.x & 63;
    int m16 = lane & 15;
    int q = lane >> 4;
    int rowbase = blockIdx.x * 64 + wave * 16;
    int n = min(rowbase + m16, N_NODES - 1);

    const uint4* y4 = (const uint4*)Y1;        // row = 8 uint4 (128 B)
    size_t rb = (size_t)n * 8 + q;
    float a0[8], a1[8];
    bset(a0, y4[rb]);                          // self contribution
    bset(a1, y4[rb + 4]);
    int s = offs[n];
    int e = min(offs[n + 1], s + 4096);        // poison-replay guard
    int i = s;
    for (; i + 4 <= e; i += 4) {
        uint4 u[4][2];
#pragma unroll
        for (int k = 0; k < 4; k++) {
            size_t r = (size_t)csr[i + k] * 8 + q;
            u[k][0] = y4[r];
            u[k][1] = y4[r + 4];
        }
#pragma unroll
        for (int k = 0; k < 4; k++) { bacc(a0, u[k][0]); bacc(a1, u[k][1]); }
    }
    for (; i < e; i++) {
        size_t r = (size_t)csr[i] * 8 + q;
        bacc(a0, y4[r]);
        bacc(a1, y4[r + 4]);
    }
    float dvn = dinv[n];
    bf8 af0 = packbf8(a0, dvn);
    bf8 af1 = packbf8(a1, dvn);

    f32x4 acc[8];
#pragma unroll
    for (int t = 0; t < 8; t++) acc[t] = (f32x4){0.f, 0.f, 0.f, 0.f};
#pragma unroll
    for (int t = 0; t < 8; t++) {
        bf8 b0 = *(const bf8*)(Wt + (size_t)(t * 16 + m16) * IN_C + q * 8);
        acc[t] = __builtin_amdgcn_mfma_f32_16x16x32_bf16(af0, b0, acc[t], 0, 0, 0);
        bf8 b1 = *(const bf8*)(Wt + (size_t)(t * 16 + m16) * IN_C + 32 + q * 8);
        acc[t] = __builtin_amdgcn_mfma_f32_16x16x32_bf16(af1, b1, acc[t], 0, 0, 0);
    }
    float dv[4];
    int rowok[4];
#pragma unroll
    for (int r = 0; r < 4; r++) {
        int row = rowbase + q * 4 + r;
        rowok[r] = (row < N_NODES);
        dv[r] = rowok[r] ? dinv[row] : 1.f;
    }
#pragma unroll
    for (int t = 0; t < 8; t++) {
        int col = t * 16 + m16;
        float bv = loadf(bias, col, ff);
#pragma unroll
        for (int r = 0; r < 4; r++) {
            int row = rowbase + q * 4 + r;
            if (rowok[r]) {
                float v = fmaxf(acc[t][r] + bv, 0.f) * dv[r];
                out[(size_t)row * HID + col] = f2bf(v);
            }
        }
    }
}

// ---- R18: fused layer 2 = gather-into-A-fragment + MFMA + mean-pool.
// Wave = 16 nodes. Lane (m16,q) gather-accumulates h1s channel slices
// [32k+q*8,+8), k=0..3 for node rowbase+m16 in registers, then
// pool(agg@W2) with bias deferred to MLP. Kills the N2 round-trip
// (25.6 MB) + one launch. ----
__global__ __launch_bounds__(256) void k_l2(const ushort* __restrict__ hs,
                                            const float* __restrict__ dinv,
                                            const int* __restrict__ offs,
                                            const int* __restrict__ csr,
                                            const ushort* __restrict__ Wt,
                                            const void* __restrict__ batch,
                                            const int* __restrict__ iflag,
                                            float* __restrict__ gsum) {
    int wide = *iflag;
    int tid = threadIdx.x;
    int wave = tid >> 6;
    int lane = tid & 63;
    int m16 = lane & 15;
    int q = lane >> 4;
    int rowbase = blockIdx.x * 64 + wave * 16;
    int n = min(rowbase + m16, N_NODES - 1);

    __shared__ float sacc[64][HID];
    __shared__ int sbg[64];
    if (tid < 64) {
        int nn = blockIdx.x * 64 + tid;
        int g = (nn < N_NODES) ? (int)batch_at(batch, nn, wide) : -1;
        sbg[tid] = (g < 0 || g >= N_GRAPHS) ? -1 : g;
    }

    const uint4* h4 = (const uint4*)hs;        // row = 16 uint4 (256 B)
    size_t rb = (size_t)n * 16 + q;
    float a[4][8];
    bset(a[0], h4[rb]);                        // self contribution
    bset(a[1], h4[rb + 4]);
    bset(a[2], h4[rb + 8]);
    bset(a[3], h4[rb + 12]);
    int s = offs[n];
    int e = min(offs[n + 1], s + 4096);        // poison-replay guard
    int i = s;
    for (; i + 2 <= e; i += 2) {
        uint4 u[2][4];
#pragma unroll
        for (int kk = 0; kk < 2; kk++) {
            size_t r = (size_t)csr[i + kk] * 16 + q;
            u[kk][0] = h4[r];
            u[kk][1] = h4[r + 4];
            u[kk][2] = h4[r + 8];
            u[kk][3] = h4[r + 12];
        }
#pragma unroll
        for (int kk = 0; kk < 2; kk++) {
#pragma unroll
            for (int k = 0; k < 4; k++) bacc(a[k], u[kk][k]);
        }
    }
    for (; i < e; i++) {
        size_t r = (size_t)csr[i] * 16 + q;
        bacc(a[0], h4[r]);
        bacc(a[1], h4[r + 4]);
        bacc(a[2], h4[r + 8]);
        bacc(a[3], h4[r + 12]);
    }
    float dvn = dinv[n];
    bf8 af0 = packbf8(a[0], dvn);
    bf8 af1 = packbf8(a[1], dvn);
    bf8 af2 = packbf8(a[2], dvn);
    bf8 af3 = packbf8(a[3], dvn);

    f32x4 acc[8];
#pragma unroll
    for (int t = 0; t < 8; t++) acc[t] = (f32x4){0.f, 0.f, 0.f, 0.f};
#pragma unroll
    for (int t = 0; t < 8; t++) {
        const ushort* wr = Wt + (size_t)(t * 16 + m16) * HID + q * 8;
        acc[t] = __builtin_amdgcn_mfma_f32_16x16x32_bf16(af0, *(const bf8*)(wr), acc[t], 0, 0, 0);
        acc[t] = __builtin_amdgcn_mfma_f32_16x16x32_bf16(af1, *(const bf8*)(wr + 32), acc[t], 0, 0, 0);
        acc[t] = __builtin_amdgcn_mfma_f32_16x16x32_bf16(af2, *(const bf8*)(wr + 64), acc[t], 0, 0, 0);
        acc[t] = __builtin_amdgcn_mfma_f32_16x16x32_bf16(af3, *(const bf8*)(wr + 96), acc[t], 0, 0, 0);
    }
#pragma unroll
    for (int t = 0; t < 8; t++) {
        int col = t * 16 + m16;
#pragma unroll
        for (int r = 0; r < 4; r++) {
            int rl = wave * 16 + q * 4 + r;
            int row = rowbase + q * 4 + r;
            sacc[rl][col] = (row < N_NODES) ? acc[t][r] : 0.f;
        }
    }
    __syncthreads();
    int col = tid & 127;
    int half = tid >> 7;
    int gcur = -1;
    float av = 0.f;
    for (int r = half * 32; r < half * 32 + 32; r++) {
        int g = sbg[r];
        if (g != gcur) {
            if (gcur >= 0) atomicAdd(&gsum[gcur * HID + col], av);
            av = 0.f;
            gcur = g;
        }
        av += sacc[r][col];
    }
    if (gcur >= 0) atomicAdd(&gsum[gcur * HID + col], av);
}

// -------- MLP head: out = relu((gsum/cnt + b2)@Wm1+bm1)@Wm2 + bm2 ; f32 -----
__global__ void k_mlp(const float* __restrict__ gsum, const void* __restrict__ batch,
                      const int* __restrict__ iflag, const void* __restrict__ b2,
                      const void* __restrict__ Wm1, const void* __restrict__ bm1,
                      const void* __restrict__ Wm2, const void* __restrict__ bm2,
                      const int* __restrict__ fflag, float* __restrict__ out) {
    int ff = *fflag;
    int wide = *iflag;
    int gr = blockIdx.x;
    int c = threadIdx.x;
    int lo = 0, hi = N_NODES;
    while (lo < hi) { int m = (lo + hi) >> 1; if (batch_at(batch, m, wide) < (i64)gr) lo = m + 1; else hi = m; }
    int s = lo;
    lo = s; hi = N_NODES;
    while (lo < hi) { int m = (lo + hi) >> 1; if (batch_at(batch, m, wide) < (i64)(gr + 1)) lo = m + 1; else hi = m; }
    float cnt = (float)(lo - s);

    __shared__ float sg[HID];
    __shared__ float r0[HID], r1[HID];
    sg[c] = gsum[gr * HID + c] / fmaxf(cnt, 1.0f) + loadf(b2, c, ff);
    __syncthreads();
    float acc = loadf(bm1, c, ff);
#pragma unroll 8
    for (int k = 0; k < HID; k++) acc += sg[k] * loadf(Wm1, k * HID + c, ff);
    float hid = fmaxf(acc, 0.f);
    r0[c] = hid * loadf(Wm2, c * OUT_C + 0, ff);
    r1[c] = hid * loadf(Wm2, c * OUT_C + 1, ff);
    __syncthreads();
    for (int off = 64; off > 0; off >>= 1) {
        if (c < off) { r0[c] += r0[c + off]; r1[c] += r1[c + off]; }
        __syncthreads();
    }
    if (c == 0) {
        out[gr * OUT_C + 0] = r0[0] + loadf(bm2, 0, ff);
        out[gr * OUT_C + 1] = r1[0] + loadf(bm2, 1, ff);
    }
}

// ---------------- launch ----------------

extern "C" void kernel_launch(void* const* d_in, const int* in_sizes, int n_in,
                              void* d_out, int out_size, void* d_ws, size_t ws_size,
                              hipStream_t stream) {
    const void* x     = d_in[0];
    const void* ei    = d_in[1];
    const void* batch = d_in[2];
    const void* W1  = d_in[3];
    const void* b1  = d_in[4];
    const void* W2  = d_in[5];
    const void* b2  = d_in[6];
    const void* Wm1 = d_in[7];
    const void* bm1 = d_in[8];
    const void* Wm2 = d_in[9];
    const void* bm2 = d_in[10];

    char* p = (char*)d_ws;
    auto alloc = [&](size_t bytes) {
        char* r = p;
        p += (bytes + 255) & ~(size_t)255;
        return r;
    };
    int*    iflag  = (int*)alloc(4);
    int*    fflag  = (int*)alloc(4);
    int*    bcnt   = (int*)alloc(NBUCK * 4);
    uint2*  bmem   = (uint2*)alloc((size_t)NBUCK * BCAP * 8);
    float*  dinv   = (float*)alloc(N_NODES * 4);
    int*    offs   = (int*)alloc((N_NODES + 1) * 4);
    int*    csr    = (int*)alloc(N_EDGES * 4);
    ushort* Wt1    = (ushort*)alloc(IN_C * HID * 2);
    ushort* Wt2    = (ushort*)alloc(HID * HID * 2);
    ushort* Y1     = (ushort*)alloc((size_t)N_NODES * IN_C * 2);
    ushort* h1s    = (ushort*)alloc((size_t)N_NODES * HID * 2);
    float*  gbuf   = (float*)alloc(N_GRAPHS * HID * 4);

    k_init<<<(N_GRAPHS * HID + 255) / 256, 256, 0, stream>>>(
        (const uint*)batch, (const uint*)x, bcnt, gbuf, iflag, fflag);
    k_binA<<<(N_EDGES + ECH - 1) / ECH, 1024, 0, stream>>>(
        ei, iflag, fflag, W1, W2, Wt1, Wt2, bcnt, bmem);
    k_binB<<<NBUCK, 1024, 0, stream>>>(bmem, bcnt, x, fflag, offs, csr, dinv, Y1);

    // fused layer 1: h1s = relu((dinv*(gather Y1 + self))@W1 + b1) * dinv
    k_l1<<<(N_NODES + 63) / 64, 256, 0, stream>>>(Y1, dinv, offs, csr, Wt1, fflag, b1, h1s);
    // fused layer 2: gsum += pool((dinv*(gather h1s + self))@W2)
    k_l2<<<(N_NODES + 63) / 64, 256, 0, stream>>>(h1s, dinv, offs, csr, Wt2, batch, iflag, gbuf);

    k_mlp<<<N_GRAPHS, HID, 0, stream>>>(gbuf, batch, iflag, b2, Wm1, bm1, Wm2, bm2, fflag, (float*)d_out);
}